// Round 4
// baseline (1043.244 us; speedup 1.0000x reference)
//
#include <hip/hip_runtime.h>

// GraphSAGE 2-layer, fp32.
// Bucketed edge partition (replaces hist/scan/fill CSR build):
//   - 782 buckets of SPAN=128 nodes (b = dst>>7), fixed padded slab per
//     bucket (cap slots) -> no prefix scan, no per-edge global atomics.
//   - k_partition: per-block LDS histogram, one global atomicAdd per
//     (block,bucket) reserves a contiguous run -> scattered writes become
//     ~10-entry runs (kills the 70MB write-allocate blowup of R3's k_fill).
//   - k_bucket_mean: one block per bucket, agg[128][64] in LDS, per-edge
//     coalesced 256B row read + LDS float atomicAdd; degree in LDS.
// Then the register-tiled GEMMs from R3 (unchanged, proven).
// d_ws: cursor[1024] | pairs[nB*cap] u32 | mean[N*64] | h[N*64]

#define SPAN        128
#define SPAN_SHIFT  7
#define PART_BLOCK  1024
#define PART_EPT    8
#define NBMAX       1024

__global__ void k_zero(int* __restrict__ p, int n) {
    int i = blockIdx.x * blockDim.x + threadIdx.x;
    if (i < n) p[i] = 0;
}

// Pack: (dst & 127) << 24 | src   (src < 2^24)
__global__ __launch_bounds__(PART_BLOCK) void k_partition(
    const int* __restrict__ src, const int* __restrict__ dst,
    int* __restrict__ cursor, unsigned int* __restrict__ pairs,
    int E, int cap)
{
    __shared__ int cnt[NBMAX];
    __shared__ int gbase[NBMAX];
    __shared__ int lcur[NBMAX];
    const int tid = threadIdx.x;
    cnt[tid] = 0; lcur[tid] = 0;
    __syncthreads();

    int sv[PART_EPT], bv[PART_EPT];
    const int e0 = blockIdx.x * (PART_BLOCK * PART_EPT) + tid;
    #pragma unroll
    for (int j = 0; j < PART_EPT; ++j) {
        int e = e0 + j * PART_BLOCK;
        bv[j] = -1;
        if (e < E) {
            int s = src[e], d = dst[e];
            bv[j] = d >> SPAN_SHIFT;
            sv[j] = s | ((d & (SPAN - 1)) << 24);
            atomicAdd(&cnt[bv[j]], 1);
        }
    }
    __syncthreads();
    if (cnt[tid] > 0) gbase[tid] = atomicAdd(&cursor[tid], cnt[tid]);
    __syncthreads();
    #pragma unroll
    for (int j = 0; j < PART_EPT; ++j) {
        if (bv[j] >= 0) {
            int r = gbase[bv[j]] + atomicAdd(&lcur[bv[j]], 1);
            if (r < cap) pairs[(size_t)bv[j] * cap + r] = (unsigned int)sv[j];
        }
    }
}

// One block per bucket. 512 threads = 8 waves; lane = feature dim (64).
// Each wave processes groups of 4 edges (4 independent 256B row loads).
__global__ __launch_bounds__(512) void k_bucket_mean(
    const float* __restrict__ x,          // [N,64]
    const unsigned int* __restrict__ pairs,
    const int* __restrict__ cursor,
    float* __restrict__ mean,             // [N,64]
    int N, int cap)
{
    __shared__ float agg[SPAN * 64];      // 32 KB
    __shared__ int cnt[SPAN];
    const int tid = threadIdx.x;
    for (int i = tid; i < SPAN * 64; i += 512) agg[i] = 0.f;
    if (tid < SPAN) cnt[tid] = 0;
    __syncthreads();

    const int b = blockIdx.x;
    int m = cursor[b]; if (m > cap) m = cap;
    const size_t pb = (size_t)b * cap;
    const int wave = tid >> 6, lane = tid & 63;

    for (int g = wave * 4; g < m; g += 32) {
        const int mm = (m - g < 4) ? (m - g) : 4;
        unsigned int p[4];
        if (mm == 4) {
            uint4 pp = *(const uint4*)&pairs[pb + g];   // cap%4==0, g%4==0
            p[0] = pp.x; p[1] = pp.y; p[2] = pp.z; p[3] = pp.w;
        } else {
            for (int k = 0; k < mm; ++k) p[k] = pairs[pb + g + k];
        }
        int dl[4]; float v[4];
        #pragma unroll
        for (int k = 0; k < 4; ++k) if (k < mm) {
            dl[k] = p[k] >> 24;
            v[k]  = x[(size_t)(p[k] & 0xFFFFFFu) * 64 + lane];
        }
        #pragma unroll
        for (int k = 0; k < 4; ++k) if (k < mm)
            atomicAdd(&agg[dl[k] * 64 + lane], v[k]);
        if (lane == 0)
            for (int k = 0; k < mm; ++k) atomicAdd(&cnt[dl[k]], 1);
    }
    __syncthreads();

    for (int r = wave; r < SPAN; r += 8) {
        int node = (b << SPAN_SHIFT) + r;
        if (node < N) {
            int c = cnt[r];
            float f = c ? 1.f / (float)c : 0.f;
            mean[(size_t)node * 64 + lane] = agg[(r << 6) + lane] * f;
        }
    }
}

// out[gm, c] = sum_k A0[gm,k]*W0[k,c] + A1[gm,k]*W1[k,c] + bias[c]
template <int DOUT, bool RELU>
__global__ __launch_bounds__(256) void k_gemm(
    const float* __restrict__ A0,   // [n,64]
    const float* __restrict__ A1,   // [n,64]
    const float* __restrict__ W0,   // [64,DOUT]
    const float* __restrict__ W1,   // [64,DOUT]
    const float* __restrict__ bias, // [DOUT]
    float* __restrict__ out,        // [n,DOUT]
    int n)
{
    constexpr int TM  = 128;
    constexpr int LDA = TM + 4;
    constexpr int LDW = DOUT + 4;
    constexpr int NT  = DOUT / 16;
    __shared__ float sA[64 * LDA];
    __shared__ float sW[64 * LDW];

    const int tid = threadIdx.x;
    const int cg  = tid & 15;
    const int mg  = tid >> 4;
    const int m0  = mg * 8;
    const int c0  = cg * NT;
    const int gm0 = blockIdx.x * TM;

    float acc[8][NT];
    #pragma unroll
    for (int i = 0; i < 8; ++i)
        #pragma unroll
        for (int j = 0; j < NT; ++j) acc[i][j] = 0.f;

    #pragma unroll
    for (int half = 0; half < 2; ++half) {
        const float* __restrict__ A = half ? A1 : A0;
        const float* __restrict__ W = half ? W1 : W0;

        for (int i = tid; i < 64 * (DOUT / 4); i += 256) {
            int k  = i / (DOUT / 4);
            int c4 = (i % (DOUT / 4)) * 4;
            float4 vv = *(const float4*)&W[k * DOUT + c4];
            *(float4*)&sW[k * LDW + c4] = vv;
        }
        for (int i = tid; i < TM * 16; i += 256) {
            int m  = i >> 4;
            int k4 = (i & 15) << 2;
            int gm = gm0 + m;
            float4 vv = make_float4(0.f, 0.f, 0.f, 0.f);
            if (gm < n) vv = *(const float4*)&A[(size_t)gm * 64 + k4];
            sA[(k4 + 0) * LDA + m] = vv.x;
            sA[(k4 + 1) * LDA + m] = vv.y;
            sA[(k4 + 2) * LDA + m] = vv.z;
            sA[(k4 + 3) * LDA + m] = vv.w;
        }
        __syncthreads();

        #pragma unroll 8
        for (int k = 0; k < 64; ++k) {
            float4 a0 = *(const float4*)&sA[k * LDA + m0];
            float4 a1 = *(const float4*)&sA[k * LDA + m0 + 4];
            float wv[NT];
            #pragma unroll
            for (int j = 0; j < NT; ++j) wv[j] = sW[k * LDW + c0 + j];
            float am[8] = {a0.x, a0.y, a0.z, a0.w, a1.x, a1.y, a1.z, a1.w};
            #pragma unroll
            for (int i = 0; i < 8; ++i)
                #pragma unroll
                for (int j = 0; j < NT; ++j)
                    acc[i][j] += am[i] * wv[j];
        }
        __syncthreads();
    }

    #pragma unroll
    for (int i = 0; i < 8; ++i) {
        int gm = gm0 + m0 + i;
        if (gm < n) {
            #pragma unroll
            for (int j = 0; j < NT; ++j) {
                float v = acc[i][j] + bias[c0 + j];
                if (RELU) v = fmaxf(v, 0.f);
                out[(size_t)gm * DOUT + c0 + j] = v;
            }
        }
    }
}

extern "C" void kernel_launch(void* const* d_in, const int* in_sizes, int n_in,
                              void* d_out, int out_size, void* d_ws, size_t ws_size,
                              hipStream_t stream) {
    const float* feat = (const float*)d_in[0];
    const int*   src  = (const int*)d_in[1];
    const int*   dst  = (const int*)d_in[2];
    const float* ws1  = (const float*)d_in[3];
    const float* wn1  = (const float*)d_in[4];
    const float* b1   = (const float*)d_in[5];
    const float* ws2  = (const float*)d_in[6];
    const float* wn2  = (const float*)d_in[7];
    const float* b2   = (const float*)d_in[8];
    float* out = (float*)d_out;

    const int N = in_sizes[0] / 64;
    const int E = in_sizes[1];
    const int nB = (N + SPAN - 1) >> SPAN_SHIFT;   // 782 for N=100000

    // cap: 1.25x mean bucket load, rounded to 64; shrink if ws is tight.
    int cap = ((E + nB - 1) / nB);
    cap = ((cap + cap / 4) + 63) & ~63;
    {
        size_t fixedBytes = NBMAX * 4 + (size_t)N * 64 * 4 * 2 + 1024;
        size_t remain = (ws_size > fixedBytes) ? (ws_size - fixedBytes) : 0;
        size_t capMax = remain / ((size_t)nB * 4);
        if ((size_t)cap > capMax) cap = (int)(capMax & ~(size_t)3);
    }

    char* base = (char*)d_ws;
    int* cursor = (int*)base;                              // [NBMAX]
    unsigned int* pairs = (unsigned int*)(base + NBMAX * 4);
    size_t mOff = ((size_t)NBMAX * 4 + (size_t)nB * cap * 4 + 255) & ~(size_t)255;
    float* mean = (float*)(base + mOff);                   // [N,64]
    float* h    = mean + (size_t)N * 64;                   // [N,64]

    k_zero<<<1, NBMAX, 0, stream>>>(cursor, NBMAX);
    const int pblocks = (E + PART_BLOCK * PART_EPT - 1) / (PART_BLOCK * PART_EPT);
    k_partition<<<pblocks, PART_BLOCK, 0, stream>>>(src, dst, cursor, pairs, E, cap);

    const int tblocks = (N + 127) / 128;
    // layer 1
    k_bucket_mean<<<nB, 512, 0, stream>>>(feat, pairs, cursor, mean, N, cap);
    k_gemm<64, true ><<<tblocks, 256, 0, stream>>>(feat, mean, ws1, wn1, b1, h, N);
    // layer 2
    k_bucket_mean<<<nB, 512, 0, stream>>>(h, pairs, cursor, mean, N, cap);
    k_gemm<32, false><<<tblocks, 256, 0, stream>>>(h, mean, ws2, wn2, b2, out, N);
}

// Round 5
// 268.977 us; speedup vs baseline: 3.8786x; 3.8786x over previous
//
#include <hip/hip_runtime.h>

// GraphSAGE 2-layer, fp32.
// Pipeline:
//   k_partition  : bucket edges by dst>>7 into fixed slabs (packed
//                  (dlocal<<24|src)); per-block LDS hist + one global atomic
//                  per (block,bucket) -> short contiguous write runs.
//   k_bucket_csr : per bucket, sort slab by dlocal entirely in LDS
//                  (hist -> scan -> scatter), write back IN PLACE coalesced;
//                  emit starts[node], degs[node].
//   k_gather_mean4: wave-per-node register accumulation. Lane = (edge-slot,
//                  dim-quad): 4 edge rows per float4 VMEM instr (1KB/instr),
//                  cross-slot reduce via __shfl_xor(16|32). NO atomics in the
//                  hot loop (R4's LDS-atomic agg was 5x slower).
//   k_gemm       : 128-node register-tiled fp32 transform (proven R3).
// d_ws: cursor[1024] | pairs[nB*cap] u32 | starts[N] | degs[N] | mean[N*64] | h[N*64]

#define SPAN        128
#define SPAN_SHIFT  7
#define PART_BLOCK  1024
#define PART_EPT    8
#define NBMAX       1024

__global__ void k_zero(int* __restrict__ p, int n) {
    int i = blockIdx.x * blockDim.x + threadIdx.x;
    if (i < n) p[i] = 0;
}

// Pack: (dst & 127) << 24 | src   (src < 2^24)
__global__ __launch_bounds__(PART_BLOCK) void k_partition(
    const int* __restrict__ src, const int* __restrict__ dst,
    int* __restrict__ cursor, unsigned int* __restrict__ pairs,
    int E, int cap)
{
    __shared__ int cnt[NBMAX];
    __shared__ int gbase[NBMAX];
    __shared__ int lcur[NBMAX];
    const int tid = threadIdx.x;
    cnt[tid] = 0; lcur[tid] = 0;
    __syncthreads();

    int sv[PART_EPT], bv[PART_EPT];
    const int e0 = blockIdx.x * (PART_BLOCK * PART_EPT) + tid;
    #pragma unroll
    for (int j = 0; j < PART_EPT; ++j) {
        int e = e0 + j * PART_BLOCK;
        bv[j] = -1;
        if (e < E) {
            int s = src[e], d = dst[e];
            bv[j] = d >> SPAN_SHIFT;
            sv[j] = s | ((d & (SPAN - 1)) << 24);
            atomicAdd(&cnt[bv[j]], 1);
        }
    }
    __syncthreads();
    if (cnt[tid] > 0) gbase[tid] = atomicAdd(&cursor[tid], cnt[tid]);
    __syncthreads();
    #pragma unroll
    for (int j = 0; j < PART_EPT; ++j) {
        if (bv[j] >= 0) {
            int r = gbase[bv[j]] + atomicAdd(&lcur[bv[j]], 1);
            if (r < cap) pairs[(size_t)bv[j] * cap + r] = (unsigned int)sv[j];
        }
    }
}

// One block per bucket: sort slab by dlocal in LDS, write back in place
// (coalesced), emit starts/degs. Dynamic LDS: cap u32 entries.
__global__ __launch_bounds__(256) void k_bucket_csr(
    unsigned int* __restrict__ pairs,   // in: packed; out: src sorted by dlocal
    const int* __restrict__ cursor,
    int* __restrict__ starts, int* __restrict__ degs,
    int N, int cap)
{
    __shared__ int cnt[SPAN];
    __shared__ int pref[SPAN];
    __shared__ int lcur[SPAN];
    extern __shared__ unsigned int sorted[];
    const int tid = threadIdx.x;
    const int b = blockIdx.x;
    if (tid < SPAN) { cnt[tid] = 0; lcur[tid] = 0; }
    __syncthreads();

    int m = cursor[b]; if (m > cap) m = cap;
    const size_t pb = (size_t)b * cap;

    for (int i = tid; i < m; i += 256)
        atomicAdd(&cnt[pairs[pb + i] >> 24], 1);
    __syncthreads();

    // inclusive scan of cnt -> pref (Hillis-Steele over 128, block-uniform)
    if (tid < SPAN) pref[tid] = cnt[tid];
    __syncthreads();
    for (int off = 1; off < SPAN; off <<= 1) {
        int v = 0;
        if (tid < SPAN && tid >= off) v = pref[tid - off];
        __syncthreads();
        if (tid < SPAN) pref[tid] += v;
        __syncthreads();
    }

    for (int i = tid; i < m; i += 256) {
        unsigned int p = pairs[pb + i];
        int r = p >> 24;
        int base = (r == 0) ? 0 : pref[r - 1];
        int pos = base + atomicAdd(&lcur[r], 1);
        sorted[pos] = p & 0xFFFFFFu;
    }
    __syncthreads();
    for (int i = tid; i < m; i += 256) pairs[pb + i] = sorted[i];
    if (tid < SPAN) {
        int node = (b << SPAN_SHIFT) + tid;
        if (node < N) {
            int base = (tid == 0) ? 0 : pref[tid - 1];
            starts[node] = (int)pb + base;
            degs[node]   = cnt[tid];
        }
    }
}

// Wave-per-node mean. lane = (edge-slot g=lane>>4, dim-quad d4=(lane&15)*4).
// Each iteration: 4 neighbor rows via one float4 load (1KB/wave-instr).
__global__ __launch_bounds__(256) void k_gather_mean4(
    const float* __restrict__ x,              // [N,64]
    const unsigned int* __restrict__ esrc,    // sorted src per bucket slab
    const int* __restrict__ starts,
    const int* __restrict__ degs,
    float* __restrict__ mean,                 // [N,64]
    int n)
{
    const int w = threadIdx.x >> 6, lane = threadIdx.x & 63;
    const int v = blockIdx.x * 4 + w;
    if (v >= n) return;
    const int beg = starts[v], deg = degs[v];
    const int g  = lane >> 4;
    const int d4 = (lane & 15) << 2;
    float4 acc = make_float4(0.f, 0.f, 0.f, 0.f);
    const int end = beg + deg;
    for (int e = beg + g; e < end; e += 4) {
        int s = (int)esrc[e];
        float4 vv = *(const float4*)&x[(size_t)s * 64 + d4];
        acc.x += vv.x; acc.y += vv.y; acc.z += vv.z; acc.w += vv.w;
    }
    acc.x += __shfl_xor(acc.x, 16); acc.y += __shfl_xor(acc.y, 16);
    acc.z += __shfl_xor(acc.z, 16); acc.w += __shfl_xor(acc.w, 16);
    acc.x += __shfl_xor(acc.x, 32); acc.y += __shfl_xor(acc.y, 32);
    acc.z += __shfl_xor(acc.z, 32); acc.w += __shfl_xor(acc.w, 32);
    if (lane < 16) {
        float f = deg ? 1.f / (float)deg : 0.f;
        float4 r = make_float4(acc.x * f, acc.y * f, acc.z * f, acc.w * f);
        *(float4*)&mean[(size_t)v * 64 + d4] = r;
    }
}

// out[gm, c] = sum_k A0[gm,k]*W0[k,c] + A1[gm,k]*W1[k,c] + bias[c]
template <int DOUT, bool RELU>
__global__ __launch_bounds__(256) void k_gemm(
    const float* __restrict__ A0, const float* __restrict__ A1,
    const float* __restrict__ W0, const float* __restrict__ W1,
    const float* __restrict__ bias, float* __restrict__ out, int n)
{
    constexpr int TM  = 128;
    constexpr int LDA = TM + 4;
    constexpr int LDW = DOUT + 4;
    constexpr int NT  = DOUT / 16;
    __shared__ float sA[64 * LDA];
    __shared__ float sW[64 * LDW];

    const int tid = threadIdx.x;
    const int cg  = tid & 15;
    const int mg  = tid >> 4;
    const int m0  = mg * 8;
    const int c0  = cg * NT;
    const int gm0 = blockIdx.x * TM;

    float acc[8][NT];
    #pragma unroll
    for (int i = 0; i < 8; ++i)
        #pragma unroll
        for (int j = 0; j < NT; ++j) acc[i][j] = 0.f;

    #pragma unroll
    for (int half = 0; half < 2; ++half) {
        const float* __restrict__ A = half ? A1 : A0;
        const float* __restrict__ W = half ? W1 : W0;

        for (int i = tid; i < 64 * (DOUT / 4); i += 256) {
            int k  = i / (DOUT / 4);
            int c4 = (i % (DOUT / 4)) * 4;
            float4 vv = *(const float4*)&W[k * DOUT + c4];
            *(float4*)&sW[k * LDW + c4] = vv;
        }
        for (int i = tid; i < TM * 16; i += 256) {
            int m  = i >> 4;
            int k4 = (i & 15) << 2;
            int gm = gm0 + m;
            float4 vv = make_float4(0.f, 0.f, 0.f, 0.f);
            if (gm < n) vv = *(const float4*)&A[(size_t)gm * 64 + k4];
            sA[(k4 + 0) * LDA + m] = vv.x;
            sA[(k4 + 1) * LDA + m] = vv.y;
            sA[(k4 + 2) * LDA + m] = vv.z;
            sA[(k4 + 3) * LDA + m] = vv.w;
        }
        __syncthreads();

        #pragma unroll 8
        for (int k = 0; k < 64; ++k) {
            float4 a0 = *(const float4*)&sA[k * LDA + m0];
            float4 a1 = *(const float4*)&sA[k * LDA + m0 + 4];
            float wv[NT];
            #pragma unroll
            for (int j = 0; j < NT; ++j) wv[j] = sW[k * LDW + c0 + j];
            float am[8] = {a0.x, a0.y, a0.z, a0.w, a1.x, a1.y, a1.z, a1.w};
            #pragma unroll
            for (int i = 0; i < 8; ++i)
                #pragma unroll
                for (int j = 0; j < NT; ++j)
                    acc[i][j] += am[i] * wv[j];
        }
        __syncthreads();
    }

    #pragma unroll
    for (int i = 0; i < 8; ++i) {
        int gm = gm0 + m0 + i;
        if (gm < n) {
            #pragma unroll
            for (int j = 0; j < NT; ++j) {
                float v = acc[i][j] + bias[c0 + j];
                if (RELU) v = fmaxf(v, 0.f);
                out[(size_t)gm * DOUT + c0 + j] = v;
            }
        }
    }
}

extern "C" void kernel_launch(void* const* d_in, const int* in_sizes, int n_in,
                              void* d_out, int out_size, void* d_ws, size_t ws_size,
                              hipStream_t stream) {
    const float* feat = (const float*)d_in[0];
    const int*   src  = (const int*)d_in[1];
    const int*   dst  = (const int*)d_in[2];
    const float* ws1  = (const float*)d_in[3];
    const float* wn1  = (const float*)d_in[4];
    const float* b1   = (const float*)d_in[5];
    const float* ws2  = (const float*)d_in[6];
    const float* wn2  = (const float*)d_in[7];
    const float* b2   = (const float*)d_in[8];
    float* out = (float*)d_out;

    const int N = in_sizes[0] / 64;
    const int E = in_sizes[1];
    const int nB = (N + SPAN - 1) >> SPAN_SHIFT;   // 782 for N=100000

    // cap: 1.25x mean bucket load, rounded to 64; clamp to fit workspace.
    int cap = ((E + nB - 1) / nB);
    cap = ((cap + cap / 4) + 63) & ~63;
    {
        size_t fixedBytes = NBMAX * 4 + (size_t)N * 8 + (size_t)N * 64 * 4 * 2 + 2048;
        size_t remain = (ws_size > fixedBytes) ? (ws_size - fixedBytes) : 0;
        size_t capMax = remain / ((size_t)nB * 4);
        if ((size_t)cap > capMax) cap = (int)(capMax & ~(size_t)3);
    }

    char* base = (char*)d_ws;
    int* cursor = (int*)base;                               // [NBMAX]
    unsigned int* pairs = (unsigned int*)(base + NBMAX * 4);
    size_t sOff = ((size_t)NBMAX * 4 + (size_t)nB * cap * 4 + 255) & ~(size_t)255;
    int* starts = (int*)(base + sOff);                      // [N]
    int* degs   = starts + N;                               // [N]
    size_t mOff = (sOff + (size_t)N * 8 + 255) & ~(size_t)255;
    float* mean = (float*)(base + mOff);                    // [N,64]
    float* h    = mean + (size_t)N * 64;                    // [N,64]

    k_zero<<<1, NBMAX, 0, stream>>>(cursor, NBMAX);
    const int pblocks = (E + PART_BLOCK * PART_EPT - 1) / (PART_BLOCK * PART_EPT);
    k_partition<<<pblocks, PART_BLOCK, 0, stream>>>(src, dst, cursor, pairs, E, cap);
    k_bucket_csr<<<nB, 256, (size_t)cap * 4, stream>>>(pairs, cursor, starts, degs, N, cap);

    const int gblocks = (N + 3) / 4;
    const int tblocks = (N + 127) / 128;
    // layer 1
    k_gather_mean4<<<gblocks, 256, 0, stream>>>(feat, pairs, starts, degs, mean, N);
    k_gemm<64, true ><<<tblocks, 256, 0, stream>>>(feat, mean, ws1, wn1, b1, h, N);
    // layer 2
    k_gather_mean4<<<gblocks, 256, 0, stream>>>(h, pairs, starts, degs, mean, N);
    k_gemm<32, false><<<tblocks, 256, 0, stream>>>(h, mean, ws2, wn2, b2, out, N);
}

// Round 6
// 263.642 us; speedup vs baseline: 3.9570x; 1.0202x over previous
//
#include <hip/hip_runtime.h>

// GraphSAGE 2-layer, fp32 compute, bf16 gather tables.
// Key identity: mean(x)@W == mean(x@W)  (linearity) -> gather smaller rows.
//   k_partition   : bucket edges by dst>>7 into fixed slabs (packed
//                   (dlocal<<24|src)); per-block LDS hist + one global atomic
//                   per (block,bucket).
//   k_bucket_csr  : per bucket, LDS counting-sort by dlocal, in-place
//                   coalesced writeback; emit starts/degs.
//   k_cvt_bf16    : xh = bf16(x)  [N,64] -> 128B rows (half the gather bytes).
//   k_gather_b64  : wave-per-node mean of bf16 rows, fp32 accum, no atomics.
//   k_gemm        : h = relu(x@Ws1 + mean1@Wn1 + b1)  (two-operand, fp32).
//   k_gemm1<bf16> : t2 = bf16(h@Wn2)  [N,32] -> 64B rows (quarter bytes).
//   k_gather_b32  : meanT = mean of t2 rows, fp32.
//   k_gemm1<add>  : out = h@Ws2 + meanT + b2.
// d_ws: cursor[1024] | pairs[nB*cap] | starts[N] | degs[N] | mean[N*64]f32
//       (reused as meanT[N*32]) | h[N*64]f32 | xh[N*64]bf16 (reused as t2)

#define SPAN        128
#define SPAN_SHIFT  7
#define PART_BLOCK  1024
#define PART_EPT    4
#define NBMAX       1024

__device__ __forceinline__ unsigned bf16_rne(float f) {
    unsigned u = __float_as_uint(f);
    return (u + 0x7FFFu + ((u >> 16) & 1u)) >> 16;
}
__device__ __forceinline__ float bf_lo(unsigned u) { return __uint_as_float(u << 16); }
__device__ __forceinline__ float bf_hi(unsigned u) { return __uint_as_float(u & 0xFFFF0000u); }

__global__ void k_zero(int* __restrict__ p, int n) {
    int i = blockIdx.x * blockDim.x + threadIdx.x;
    if (i < n) p[i] = 0;
}

// x[N*64] f32 -> xh[N*64] bf16 (RNE). 8 elems/thread.
__global__ __launch_bounds__(256) void k_cvt_bf16(
    const float* __restrict__ x, unsigned short* __restrict__ xh, long total8)
{
    long i = (long)blockIdx.x * blockDim.x + threadIdx.x;
    if (i >= total8) return;
    const float4 a = ((const float4*)x)[i * 2];
    const float4 b = ((const float4*)x)[i * 2 + 1];
    uint4 o;
    o.x = bf16_rne(a.x) | (bf16_rne(a.y) << 16);
    o.y = bf16_rne(a.z) | (bf16_rne(a.w) << 16);
    o.z = bf16_rne(b.x) | (bf16_rne(b.y) << 16);
    o.w = bf16_rne(b.z) | (bf16_rne(b.w) << 16);
    ((uint4*)xh)[i] = o;
}

// Pack: (dst & 127) << 24 | src   (src < 2^24)
__global__ __launch_bounds__(PART_BLOCK) void k_partition(
    const int* __restrict__ src, const int* __restrict__ dst,
    int* __restrict__ cursor, unsigned int* __restrict__ pairs,
    int E, int cap)
{
    __shared__ int cnt[NBMAX];
    __shared__ int gbase[NBMAX];
    __shared__ int lcur[NBMAX];
    const int tid = threadIdx.x;
    cnt[tid] = 0; lcur[tid] = 0;
    __syncthreads();

    int sv[PART_EPT], bv[PART_EPT];
    const int e0 = blockIdx.x * (PART_BLOCK * PART_EPT) + tid;
    #pragma unroll
    for (int j = 0; j < PART_EPT; ++j) {
        int e = e0 + j * PART_BLOCK;
        bv[j] = -1;
        if (e < E) {
            int s = src[e], d = dst[e];
            bv[j] = d >> SPAN_SHIFT;
            sv[j] = s | ((d & (SPAN - 1)) << 24);
            atomicAdd(&cnt[bv[j]], 1);
        }
    }
    __syncthreads();
    if (cnt[tid] > 0) gbase[tid] = atomicAdd(&cursor[tid], cnt[tid]);
    __syncthreads();
    #pragma unroll
    for (int j = 0; j < PART_EPT; ++j) {
        if (bv[j] >= 0) {
            int r = gbase[bv[j]] + atomicAdd(&lcur[bv[j]], 1);
            if (r < cap) pairs[(size_t)bv[j] * cap + r] = (unsigned int)sv[j];
        }
    }
}

// One block per bucket: counting-sort slab by dlocal in LDS, write back
// in place (coalesced), emit starts/degs.
__global__ __launch_bounds__(256) void k_bucket_csr(
    unsigned int* __restrict__ pairs,
    const int* __restrict__ cursor,
    int* __restrict__ starts, int* __restrict__ degs,
    int N, int cap)
{
    __shared__ int cnt[SPAN];
    __shared__ int pref[SPAN];
    __shared__ int lcur[SPAN];
    extern __shared__ unsigned int sorted[];
    const int tid = threadIdx.x;
    const int b = blockIdx.x;
    if (tid < SPAN) { cnt[tid] = 0; lcur[tid] = 0; }
    __syncthreads();

    int m = cursor[b]; if (m > cap) m = cap;
    const size_t pb = (size_t)b * cap;

    for (int i = tid; i < m; i += 256)
        atomicAdd(&cnt[pairs[pb + i] >> 24], 1);
    __syncthreads();

    if (tid < SPAN) pref[tid] = cnt[tid];
    __syncthreads();
    for (int off = 1; off < SPAN; off <<= 1) {
        int v = 0;
        if (tid < SPAN && tid >= off) v = pref[tid - off];
        __syncthreads();
        if (tid < SPAN) pref[tid] += v;
        __syncthreads();
    }

    for (int i = tid; i < m; i += 256) {
        unsigned int p = pairs[pb + i];
        int r = p >> 24;
        int base = (r == 0) ? 0 : pref[r - 1];
        int pos = base + atomicAdd(&lcur[r], 1);
        sorted[pos] = p & 0xFFFFFFu;
    }
    __syncthreads();
    for (int i = tid; i < m; i += 256) pairs[pb + i] = sorted[i];
    if (tid < SPAN) {
        int node = (b << SPAN_SHIFT) + tid;
        if (node < N) {
            int base = (tid == 0) ? 0 : pref[tid - 1];
            starts[node] = (int)pb + base;
            degs[node]   = cnt[tid];
        }
    }
}

// Wave-per-node mean over bf16 [*,64] rows. 16 lanes x 8B = one 128B row;
// 4 rows per wave-instr. fp32 accum, shfl reduce, lanes<16 write float4.
__global__ __launch_bounds__(256) void k_gather_b64(
    const unsigned short* __restrict__ xh,    // [N,64] bf16
    const unsigned int* __restrict__ esrc,
    const int* __restrict__ starts, const int* __restrict__ degs,
    float* __restrict__ mean, int n)          // [n,64] f32
{
    const int w = threadIdx.x >> 6, lane = threadIdx.x & 63;
    const int v = blockIdx.x * 4 + w;
    if (v >= n) return;
    const int beg = starts[v], deg = degs[v];
    const int g = lane >> 4, c = lane & 15;
    float4 acc = make_float4(0.f, 0.f, 0.f, 0.f);
    const int end = beg + deg;
    for (int e = beg + g; e < end; e += 4) {
        int s = (int)esrc[e];
        uint2 u = *(const uint2*)&xh[(size_t)s * 64 + c * 4];
        acc.x += bf_lo(u.x); acc.y += bf_hi(u.x);
        acc.z += bf_lo(u.y); acc.w += bf_hi(u.y);
    }
    acc.x += __shfl_xor(acc.x, 16); acc.y += __shfl_xor(acc.y, 16);
    acc.z += __shfl_xor(acc.z, 16); acc.w += __shfl_xor(acc.w, 16);
    acc.x += __shfl_xor(acc.x, 32); acc.y += __shfl_xor(acc.y, 32);
    acc.z += __shfl_xor(acc.z, 32); acc.w += __shfl_xor(acc.w, 32);
    if (lane < 16) {
        float f = deg ? 1.f / (float)deg : 0.f;
        *(float4*)&mean[(size_t)v * 64 + c * 4] =
            make_float4(acc.x * f, acc.y * f, acc.z * f, acc.w * f);
    }
}

// Wave-per-node mean over bf16 [*,32] rows. 8 lanes x 8B = one 64B row;
// 8 rows per wave-instr.
__global__ __launch_bounds__(256) void k_gather_b32(
    const unsigned short* __restrict__ t2,    // [N,32] bf16
    const unsigned int* __restrict__ esrc,
    const int* __restrict__ starts, const int* __restrict__ degs,
    float* __restrict__ meanT, int n)         // [n,32] f32
{
    const int w = threadIdx.x >> 6, lane = threadIdx.x & 63;
    const int v = blockIdx.x * 4 + w;
    if (v >= n) return;
    const int beg = starts[v], deg = degs[v];
    const int g = lane >> 3, c = lane & 7;
    float4 acc = make_float4(0.f, 0.f, 0.f, 0.f);
    const int end = beg + deg;
    for (int e = beg + g; e < end; e += 8) {
        int s = (int)esrc[e];
        uint2 u = *(const uint2*)&t2[(size_t)s * 32 + c * 4];
        acc.x += bf_lo(u.x); acc.y += bf_hi(u.x);
        acc.z += bf_lo(u.y); acc.w += bf_hi(u.y);
    }
    acc.x += __shfl_xor(acc.x, 8);  acc.y += __shfl_xor(acc.y, 8);
    acc.z += __shfl_xor(acc.z, 8);  acc.w += __shfl_xor(acc.w, 8);
    acc.x += __shfl_xor(acc.x, 16); acc.y += __shfl_xor(acc.y, 16);
    acc.z += __shfl_xor(acc.z, 16); acc.w += __shfl_xor(acc.w, 16);
    acc.x += __shfl_xor(acc.x, 32); acc.y += __shfl_xor(acc.y, 32);
    acc.z += __shfl_xor(acc.z, 32); acc.w += __shfl_xor(acc.w, 32);
    if (lane < 8) {
        float f = deg ? 1.f / (float)deg : 0.f;
        *(float4*)&meanT[(size_t)v * 32 + c * 4] =
            make_float4(acc.x * f, acc.y * f, acc.z * f, acc.w * f);
    }
}

// Two-operand GEMM: out = A0@W0 + A1@W1 + bias (layer 1, fp32, RELU).
template <int DOUT, bool RELU>
__global__ __launch_bounds__(256) void k_gemm(
    const float* __restrict__ A0, const float* __restrict__ A1,
    const float* __restrict__ W0, const float* __restrict__ W1,
    const float* __restrict__ bias, float* __restrict__ out, int n)
{
    constexpr int TM  = 128;
    constexpr int LDA = TM + 4;
    constexpr int LDW = DOUT + 4;
    constexpr int NT  = DOUT / 16;
    __shared__ float sA[64 * LDA];
    __shared__ float sW[64 * LDW];

    const int tid = threadIdx.x;
    const int cg  = tid & 15;
    const int mg  = tid >> 4;
    const int m0  = mg * 8;
    const int c0  = cg * NT;
    const int gm0 = blockIdx.x * TM;

    float acc[8][NT];
    #pragma unroll
    for (int i = 0; i < 8; ++i)
        #pragma unroll
        for (int j = 0; j < NT; ++j) acc[i][j] = 0.f;

    #pragma unroll
    for (int half = 0; half < 2; ++half) {
        const float* __restrict__ A = half ? A1 : A0;
        const float* __restrict__ W = half ? W1 : W0;
        for (int i = tid; i < 64 * (DOUT / 4); i += 256) {
            int k  = i / (DOUT / 4);
            int c4 = (i % (DOUT / 4)) * 4;
            *(float4*)&sW[k * LDW + c4] = *(const float4*)&W[k * DOUT + c4];
        }
        for (int i = tid; i < TM * 16; i += 256) {
            int m  = i >> 4;
            int k4 = (i & 15) << 2;
            int gm = gm0 + m;
            float4 vv = make_float4(0.f, 0.f, 0.f, 0.f);
            if (gm < n) vv = *(const float4*)&A[(size_t)gm * 64 + k4];
            sA[(k4 + 0) * LDA + m] = vv.x;
            sA[(k4 + 1) * LDA + m] = vv.y;
            sA[(k4 + 2) * LDA + m] = vv.z;
            sA[(k4 + 3) * LDA + m] = vv.w;
        }
        __syncthreads();
        #pragma unroll 8
        for (int k = 0; k < 64; ++k) {
            float4 a0 = *(const float4*)&sA[k * LDA + m0];
            float4 a1 = *(const float4*)&sA[k * LDA + m0 + 4];
            float wv[NT];
            #pragma unroll
            for (int j = 0; j < NT; ++j) wv[j] = sW[k * LDW + c0 + j];
            float am[8] = {a0.x, a0.y, a0.z, a0.w, a1.x, a1.y, a1.z, a1.w};
            #pragma unroll
            for (int i = 0; i < 8; ++i)
                #pragma unroll
                for (int j = 0; j < NT; ++j)
                    acc[i][j] += am[i] * wv[j];
        }
        __syncthreads();
    }

    #pragma unroll
    for (int i = 0; i < 8; ++i) {
        int gm = gm0 + m0 + i;
        if (gm < n) {
            #pragma unroll
            for (int j = 0; j < NT; ++j) {
                float v = acc[i][j] + bias[c0 + j];
                if (RELU) v = fmaxf(v, 0.f);
                out[(size_t)gm * DOUT + c0 + j] = v;
            }
        }
    }
}

// Single-operand GEMM: out = A@W [+ bias] [+ addm], fp32 or bf16 output.
template <int DOUT, bool USE_BIAS, bool ADDM, bool BF16OUT>
__global__ __launch_bounds__(256) void k_gemm1(
    const float* __restrict__ A, const float* __restrict__ W,
    const float* __restrict__ bias, const float* __restrict__ addm,
    void* __restrict__ outp, int n)
{
    constexpr int TM  = 128;
    constexpr int LDA = TM + 4;
    constexpr int LDW = DOUT + 4;
    constexpr int NT  = DOUT / 16;
    __shared__ float sA[64 * LDA];
    __shared__ float sW[64 * LDW];

    const int tid = threadIdx.x;
    const int cg  = tid & 15;
    const int mg  = tid >> 4;
    const int m0  = mg * 8;
    const int c0  = cg * NT;
    const int gm0 = blockIdx.x * TM;

    float acc[8][NT];
    #pragma unroll
    for (int i = 0; i < 8; ++i)
        #pragma unroll
        for (int j = 0; j < NT; ++j) acc[i][j] = 0.f;

    for (int i = tid; i < 64 * (DOUT / 4); i += 256) {
        int k  = i / (DOUT / 4);
        int c4 = (i % (DOUT / 4)) * 4;
        *(float4*)&sW[k * LDW + c4] = *(const float4*)&W[k * DOUT + c4];
    }
    for (int i = tid; i < TM * 16; i += 256) {
        int m  = i >> 4;
        int k4 = (i & 15) << 2;
        int gm = gm0 + m;
        float4 vv = make_float4(0.f, 0.f, 0.f, 0.f);
        if (gm < n) vv = *(const float4*)&A[(size_t)gm * 64 + k4];
        sA[(k4 + 0) * LDA + m] = vv.x;
        sA[(k4 + 1) * LDA + m] = vv.y;
        sA[(k4 + 2) * LDA + m] = vv.z;
        sA[(k4 + 3) * LDA + m] = vv.w;
    }
    __syncthreads();
    #pragma unroll 8
    for (int k = 0; k < 64; ++k) {
        float4 a0 = *(const float4*)&sA[k * LDA + m0];
        float4 a1 = *(const float4*)&sA[k * LDA + m0 + 4];
        float wv[NT];
        #pragma unroll
        for (int j = 0; j < NT; ++j) wv[j] = sW[k * LDW + c0 + j];
        float am[8] = {a0.x, a0.y, a0.z, a0.w, a1.x, a1.y, a1.z, a1.w};
        #pragma unroll
        for (int i = 0; i < 8; ++i)
            #pragma unroll
            for (int j = 0; j < NT; ++j)
                acc[i][j] += am[i] * wv[j];
    }

    #pragma unroll
    for (int i = 0; i < 8; ++i) {
        int gm = gm0 + m0 + i;
        if (gm < n) {
            float v[NT];
            #pragma unroll
            for (int j = 0; j < NT; ++j) {
                v[j] = acc[i][j];
                if (USE_BIAS) v[j] += bias[c0 + j];
                if (ADDM)     v[j] += addm[(size_t)gm * DOUT + c0 + j];
            }
            if (BF16OUT) {
                // NT==2: pack two bf16 into one u32 store
                unsigned short* o = (unsigned short*)outp;
                unsigned pk = bf16_rne(v[0]) | (bf16_rne(v[1]) << 16);
                *(unsigned*)&o[(size_t)gm * DOUT + c0] = pk;
            } else {
                float* o = (float*)outp;
                #pragma unroll
                for (int j = 0; j < NT; ++j)
                    o[(size_t)gm * DOUT + c0 + j] = v[j];
            }
        }
    }
}

extern "C" void kernel_launch(void* const* d_in, const int* in_sizes, int n_in,
                              void* d_out, int out_size, void* d_ws, size_t ws_size,
                              hipStream_t stream) {
    const float* feat = (const float*)d_in[0];
    const int*   src  = (const int*)d_in[1];
    const int*   dst  = (const int*)d_in[2];
    const float* ws1  = (const float*)d_in[3];
    const float* wn1  = (const float*)d_in[4];
    const float* b1   = (const float*)d_in[5];
    const float* ws2  = (const float*)d_in[6];
    const float* wn2  = (const float*)d_in[7];
    const float* b2   = (const float*)d_in[8];
    float* out = (float*)d_out;

    const int N = in_sizes[0] / 64;
    const int E = in_sizes[1];
    const int nB = (N + SPAN - 1) >> SPAN_SHIFT;   // 782 for N=100000

    int cap = ((E + nB - 1) / nB);
    cap = ((cap + cap / 4) + 63) & ~63;
    {
        size_t fixedBytes = NBMAX * 4 + (size_t)N * 8
                          + (size_t)N * 64 * 4 * 2   // mean + h
                          + (size_t)N * 64 * 2       // xh
                          + 4096;
        size_t remain = (ws_size > fixedBytes) ? (ws_size - fixedBytes) : 0;
        size_t capMax = remain / ((size_t)nB * 4);
        if ((size_t)cap > capMax) cap = (int)(capMax & ~(size_t)3);
    }

    char* base = (char*)d_ws;
    int* cursor = (int*)base;                               // [NBMAX]
    unsigned int* pairs = (unsigned int*)(base + NBMAX * 4);
    size_t sOff = ((size_t)NBMAX * 4 + (size_t)nB * cap * 4 + 255) & ~(size_t)255;
    int* starts = (int*)(base + sOff);                      // [N]
    int* degs   = starts + N;                               // [N]
    size_t mOff = (sOff + (size_t)N * 8 + 255) & ~(size_t)255;
    float* mean = (float*)(base + mOff);                    // [N,64] f32; reused as meanT [N,32]
    float* h    = mean + (size_t)N * 64;                    // [N,64] f32
    unsigned short* xh = (unsigned short*)(h + (size_t)N * 64);  // [N,64] bf16; reused as t2 [N,32]
    float* meanT = mean;
    unsigned short* t2 = xh;

    k_zero<<<1, NBMAX, 0, stream>>>(cursor, NBMAX);
    const int pblocks = (E + PART_BLOCK * PART_EPT - 1) / (PART_BLOCK * PART_EPT);
    k_partition<<<pblocks, PART_BLOCK, 0, stream>>>(src, dst, cursor, pairs, E, cap);
    k_bucket_csr<<<nB, 256, (size_t)cap * 4, stream>>>(pairs, cursor, starts, degs, N, cap);

    const long total8 = (long)N * 64 / 8;
    k_cvt_bf16<<<(int)((total8 + 255) / 256), 256, 0, stream>>>(feat, xh, total8);

    const int gblocks = (N + 3) / 4;
    const int tblocks = (N + 127) / 128;

    // layer 1: mean1 = mean(bf16(x)); h = relu(x@Ws1 + mean1@Wn1 + b1)
    k_gather_b64<<<gblocks, 256, 0, stream>>>(xh, pairs, starts, degs, mean, N);
    k_gemm<64, true><<<tblocks, 256, 0, stream>>>(feat, mean, ws1, wn1, b1, h, N);

    // layer 2: t2 = bf16(h@Wn2); meanT = mean(t2); out = h@Ws2 + meanT + b2
    k_gemm1<32, false, false, true ><<<tblocks, 256, 0, stream>>>(h, wn2, nullptr, nullptr, t2, N);
    k_gather_b32<<<gblocks, 256, 0, stream>>>(t2, pairs, starts, degs, meanT, N);
    k_gemm1<32, true,  true,  false><<<tblocks, 256, 0, stream>>>(h, ws2, b2, meanT, out, N);
}

// Round 7
// 236.557 us; speedup vs baseline: 4.4101x; 1.1145x over previous
//
#include <hip/hip_runtime.h>

// GraphSAGE 2-layer, fp32 compute, bf16 gather tables.
// mean(x)@W == mean(x@W) -> layer-2 gathers 64B rows of t2=bf16(h@Wn2).
// Pipeline (6 kernels):
//   k_cvt_zero     : xh = bf16(x); block 0 zeros cursor.
//   k_partition    : bucket edges by dst>>7 into padded slabs.
//   k_bucket_csr   : per-bucket LDS counting sort -> starts/degs.
//   k_gather_b64   : wave/node mean of bf16 rows; uint4 = 8 rows/instr.
//   k_gemm_l1      : FUSED: h=relu(x@Ws1+mean@Wn1+b1); h-tile -> sA (XOR
//                    swizzle, bank-conflict-free); 2nd k-loop: t2=bf16(h@Wn2)
//                    and out=h@Ws2+b2 from the register-resident tile.
//   k_gather_b32add: mean of t2 rows (uint4 = 16 rows/instr), out += meanT.
// sA layout swizzle: chunk(m/4) ^= (k>>2)&7 -> staging writes 2-way (free),
// reads stay 16B-aligned float4.  (R6: 8-way conflicts, 2.8M cycles.)

#define SPAN        128
#define SPAN_SHIFT  7
#define PART_BLOCK  1024
#define PART_EPT    4
#define NBMAX       1024
#define LDA         132

__device__ __forceinline__ unsigned bf16_rne(float f) {
    unsigned u = __float_as_uint(f);
    return (u + 0x7FFFu + ((u >> 16) & 1u)) >> 16;
}
__device__ __forceinline__ float bf_lo(unsigned u) { return __uint_as_float(u << 16); }
__device__ __forceinline__ float bf_hi(unsigned u) { return __uint_as_float(u & 0xFFFF0000u); }
// sA address with chunk swizzle (valid when m-groups of 4 stay intact)
__device__ __forceinline__ int swA(int k, int m) {
    return k * LDA + (m ^ (((k >> 2) & 7) << 2));
}

// x[N*64] f32 -> xh bf16; block 0 zeros cursor[NBMAX].
__global__ __launch_bounds__(256) void k_cvt_zero(
    const float* __restrict__ x, unsigned short* __restrict__ xh,
    int* __restrict__ cursor, long total8)
{
    if (blockIdx.x == 0)
        for (int i = threadIdx.x; i < NBMAX; i += 256) cursor[i] = 0;
    long i = (long)blockIdx.x * blockDim.x + threadIdx.x;
    if (i >= total8) return;
    const float4 a = ((const float4*)x)[i * 2];
    const float4 b = ((const float4*)x)[i * 2 + 1];
    uint4 o;
    o.x = bf16_rne(a.x) | (bf16_rne(a.y) << 16);
    o.y = bf16_rne(a.z) | (bf16_rne(a.w) << 16);
    o.z = bf16_rne(b.x) | (bf16_rne(b.y) << 16);
    o.w = bf16_rne(b.z) | (bf16_rne(b.w) << 16);
    ((uint4*)xh)[i] = o;
}

// Pack: (dst & 127) << 24 | src   (src < 2^24)
__global__ __launch_bounds__(PART_BLOCK) void k_partition(
    const int* __restrict__ src, const int* __restrict__ dst,
    int* __restrict__ cursor, unsigned int* __restrict__ pairs,
    int E, int cap)
{
    __shared__ int cnt[NBMAX];
    __shared__ int gbase[NBMAX];
    __shared__ int lcur[NBMAX];
    const int tid = threadIdx.x;
    cnt[tid] = 0; lcur[tid] = 0;
    __syncthreads();

    int sv[PART_EPT], bv[PART_EPT];
    const int e0 = blockIdx.x * (PART_BLOCK * PART_EPT) + tid;
    #pragma unroll
    for (int j = 0; j < PART_EPT; ++j) {
        int e = e0 + j * PART_BLOCK;
        bv[j] = -1;
        if (e < E) {
            int s = src[e], d = dst[e];
            bv[j] = d >> SPAN_SHIFT;
            sv[j] = s | ((d & (SPAN - 1)) << 24);
            atomicAdd(&cnt[bv[j]], 1);
        }
    }
    __syncthreads();
    if (cnt[tid] > 0) gbase[tid] = atomicAdd(&cursor[tid], cnt[tid]);
    __syncthreads();
    #pragma unroll
    for (int j = 0; j < PART_EPT; ++j) {
        if (bv[j] >= 0) {
            int r = gbase[bv[j]] + atomicAdd(&lcur[bv[j]], 1);
            if (r < cap) pairs[(size_t)bv[j] * cap + r] = (unsigned int)sv[j];
        }
    }
}

// Per bucket: LDS counting sort by dlocal, in-place coalesced writeback.
__global__ __launch_bounds__(256) void k_bucket_csr(
    unsigned int* __restrict__ pairs,
    const int* __restrict__ cursor,
    int* __restrict__ starts, int* __restrict__ degs,
    int N, int cap)
{
    __shared__ int cnt[SPAN];
    __shared__ int pref[SPAN];
    __shared__ int lcur[SPAN];
    extern __shared__ unsigned int sorted[];
    const int tid = threadIdx.x;
    const int b = blockIdx.x;
    if (tid < SPAN) { cnt[tid] = 0; lcur[tid] = 0; }
    __syncthreads();

    int m = cursor[b]; if (m > cap) m = cap;
    const size_t pb = (size_t)b * cap;

    for (int i = tid; i < m; i += 256)
        atomicAdd(&cnt[pairs[pb + i] >> 24], 1);
    __syncthreads();

    if (tid < SPAN) pref[tid] = cnt[tid];
    __syncthreads();
    for (int off = 1; off < SPAN; off <<= 1) {
        int v = 0;
        if (tid < SPAN && tid >= off) v = pref[tid - off];
        __syncthreads();
        if (tid < SPAN) pref[tid] += v;
        __syncthreads();
    }

    for (int i = tid; i < m; i += 256) {
        unsigned int p = pairs[pb + i];
        int r = p >> 24;
        int base = (r == 0) ? 0 : pref[r - 1];
        int pos = base + atomicAdd(&lcur[r], 1);
        sorted[pos] = p & 0xFFFFFFu;
    }
    __syncthreads();
    for (int i = tid; i < m; i += 256) pairs[pb + i] = sorted[i];
    if (tid < SPAN) {
        int node = (b << SPAN_SHIFT) + tid;
        if (node < N) {
            int base = (tid == 0) ? 0 : pref[tid - 1];
            starts[node] = (int)pb + base;
            degs[node]   = cnt[tid];
        }
    }
}

// Wave/node mean over bf16 [*,64] rows. 8 lanes x 16B = row; 8 rows/instr.
__global__ __launch_bounds__(256) void k_gather_b64(
    const unsigned short* __restrict__ xh,
    const unsigned int* __restrict__ esrc,
    const int* __restrict__ starts, const int* __restrict__ degs,
    float* __restrict__ mean, int n)
{
    const int w = threadIdx.x >> 6, lane = threadIdx.x & 63;
    const int v = blockIdx.x * 4 + w;
    if (v >= n) return;
    const int beg = starts[v], deg = degs[v];
    const int g = lane >> 3, c = lane & 7;
    float a0 = 0.f, a1 = 0.f, a2 = 0.f, a3 = 0.f;
    float a4 = 0.f, a5 = 0.f, a6 = 0.f, a7 = 0.f;
    const int end = beg + deg;
    for (int e = beg + g; e < end; e += 8) {
        int s = (int)esrc[e];
        uint4 u = *(const uint4*)&xh[(size_t)s * 64 + c * 8];
        a0 += bf_lo(u.x); a1 += bf_hi(u.x);
        a2 += bf_lo(u.y); a3 += bf_hi(u.y);
        a4 += bf_lo(u.z); a5 += bf_hi(u.z);
        a6 += bf_lo(u.w); a7 += bf_hi(u.w);
    }
    #pragma unroll
    for (int d = 8; d <= 32; d <<= 1) {
        a0 += __shfl_xor(a0, d); a1 += __shfl_xor(a1, d);
        a2 += __shfl_xor(a2, d); a3 += __shfl_xor(a3, d);
        a4 += __shfl_xor(a4, d); a5 += __shfl_xor(a5, d);
        a6 += __shfl_xor(a6, d); a7 += __shfl_xor(a7, d);
    }
    if (lane < 8) {
        float f = deg ? 1.f / (float)deg : 0.f;
        *(float4*)&mean[(size_t)v * 64 + c * 8]     = make_float4(a0*f, a1*f, a2*f, a3*f);
        *(float4*)&mean[(size_t)v * 64 + c * 8 + 4] = make_float4(a4*f, a5*f, a6*f, a7*f);
    }
}

// FUSED layer-1 transform + layer-2 pre-transforms.
__global__ __launch_bounds__(256) void k_gemm_l1(
    const float* __restrict__ feat, const float* __restrict__ mean,
    const float* __restrict__ ws1, const float* __restrict__ wn1,
    const float* __restrict__ b1,
    const float* __restrict__ ws2, const float* __restrict__ wn2,
    const float* __restrict__ b2,
    float* __restrict__ h, unsigned short* __restrict__ t2,
    float* __restrict__ outp, int n)
{
    constexpr int TM   = 128;
    constexpr int LDW  = 68;     // DOUT=64 stage
    constexpr int LDW2 = 34;     // DOUT=32 stages (x2 fit in sW)
    __shared__ float sA[64 * LDA];    // 33792 B
    __shared__ float sW[64 * LDW];    // 17408 B (= 2 * 64*LDW2)

    const int tid = threadIdx.x;
    const int cg  = tid & 15;
    const int mg  = tid >> 4;
    const int m0  = mg * 8;
    const int c0  = cg * 4;
    const int gm0 = blockIdx.x * TM;

    float acc[8][4];
    #pragma unroll
    for (int i = 0; i < 8; ++i)
        #pragma unroll
        for (int j = 0; j < 4; ++j) acc[i][j] = 0.f;

    #pragma unroll
    for (int half = 0; half < 2; ++half) {
        const float* __restrict__ A = half ? mean : feat;
        const float* __restrict__ W = half ? wn1 : ws1;
        for (int i = tid; i < 64 * 16; i += 256) {
            int k  = i >> 4;
            int c4 = (i & 15) << 2;
            *(float4*)&sW[k * LDW + c4] = *(const float4*)&W[k * 64 + c4];
        }
        for (int i = tid; i < TM * 16; i += 256) {
            int m  = i >> 4;
            int k4 = (i & 15) << 2;
            int gm = gm0 + m;
            float4 vv = make_float4(0.f, 0.f, 0.f, 0.f);
            if (gm < n) vv = *(const float4*)&A[(size_t)gm * 64 + k4];
            sA[swA(k4 + 0, m)] = vv.x;
            sA[swA(k4 + 1, m)] = vv.y;
            sA[swA(k4 + 2, m)] = vv.z;
            sA[swA(k4 + 3, m)] = vv.w;
        }
        __syncthreads();
        #pragma unroll 8
        for (int k = 0; k < 64; ++k) {
            const int s = (k >> 2) & 7;
            float4 a0 = *(const float4*)&sA[k * LDA + (((2*mg)   ^ s) << 2)];
            float4 a1 = *(const float4*)&sA[k * LDA + (((2*mg+1) ^ s) << 2)];
            float wv[4];
            #pragma unroll
            for (int j = 0; j < 4; ++j) wv[j] = sW[k * LDW + c0 + j];
            float am[8] = {a0.x, a0.y, a0.z, a0.w, a1.x, a1.y, a1.z, a1.w};
            #pragma unroll
            for (int i = 0; i < 8; ++i)
                #pragma unroll
                for (int j = 0; j < 4; ++j)
                    acc[i][j] += am[i] * wv[j];
        }
        __syncthreads();
    }

    // epilogue 1: h = relu(acc + b1); store + deposit h-tile into sA
    float bb[4];
    #pragma unroll
    for (int j = 0; j < 4; ++j) bb[j] = b1[c0 + j];
    #pragma unroll
    for (int i = 0; i < 8; ++i) {
        int gm = gm0 + m0 + i;
        float hv[4];
        #pragma unroll
        for (int j = 0; j < 4; ++j) {
            hv[j] = fmaxf(acc[i][j] + bb[j], 0.f);
            sA[swA(c0 + j, m0 + i)] = hv[j];       // k=h-col, m=row
        }
        if (gm < n)
            *(float4*)&h[(size_t)gm * 64 + c0] = make_float4(hv[0], hv[1], hv[2], hv[3]);
    }
    // stage Wn2 -> sW2, Ws2 -> sW3
    float* sW2 = sW;
    float* sW3 = sW + 64 * LDW2;
    for (int i = tid; i < 64 * 8; i += 256) {
        int k  = i >> 3;
        int c4 = (i & 7) << 2;
        *(float4*)&sW2[k * LDW2 + c4] = *(const float4*)&wn2[k * 32 + c4];
        *(float4*)&sW3[k * LDW2 + c4] = *(const float4*)&ws2[k * 32 + c4];
    }
    __syncthreads();

    // second k-loop: t2 = h@Wn2 (bf16), outp = h@Ws2 + b2
    const int c2 = cg * 2;
    float acc2[8][2], acc3[8][2];
    #pragma unroll
    for (int i = 0; i < 8; ++i) {
        acc2[i][0] = acc2[i][1] = 0.f;
        acc3[i][0] = acc3[i][1] = 0.f;
    }
    #pragma unroll 8
    for (int k = 0; k < 64; ++k) {
        const int s = (k >> 2) & 7;
        float4 a0 = *(const float4*)&sA[k * LDA + (((2*mg)   ^ s) << 2)];
        float4 a1 = *(const float4*)&sA[k * LDA + (((2*mg+1) ^ s) << 2)];
        float w2a = sW2[k * LDW2 + c2], w2b = sW2[k * LDW2 + c2 + 1];
        float w3a = sW3[k * LDW2 + c2], w3b = sW3[k * LDW2 + c2 + 1];
        float am[8] = {a0.x, a0.y, a0.z, a0.w, a1.x, a1.y, a1.z, a1.w};
        #pragma unroll
        for (int i = 0; i < 8; ++i) {
            acc2[i][0] += am[i] * w2a;  acc2[i][1] += am[i] * w2b;
            acc3[i][0] += am[i] * w3a;  acc3[i][1] += am[i] * w3b;
        }
    }
    float b2a = b2[c2], b2b = b2[c2 + 1];
    #pragma unroll
    for (int i = 0; i < 8; ++i) {
        int gm = gm0 + m0 + i;
        if (gm < n) {
            unsigned pk = bf16_rne(acc2[i][0]) | (bf16_rne(acc2[i][1]) << 16);
            *(unsigned*)&t2[(size_t)gm * 32 + c2] = pk;
            outp[(size_t)gm * 32 + c2]     = acc3[i][0] + b2a;
            outp[(size_t)gm * 32 + c2 + 1] = acc3[i][1] + b2b;
        }
    }
}

// Wave/node mean over bf16 [*,32] rows (4 lanes x 16B = row; 16 rows/instr);
// adds result into outp (pre-filled with h@Ws2 + b2).
__global__ __launch_bounds__(256) void k_gather_b32add(
    const unsigned short* __restrict__ t2,
    const unsigned int* __restrict__ esrc,
    const int* __restrict__ starts, const int* __restrict__ degs,
    float* __restrict__ outp, int n)
{
    const int w = threadIdx.x >> 6, lane = threadIdx.x & 63;
    const int v = blockIdx.x * 4 + w;
    if (v >= n) return;
    const int beg = starts[v], deg = degs[v];
    if (deg == 0) return;
    const int g = lane >> 2, c = lane & 3;
    float a0 = 0.f, a1 = 0.f, a2 = 0.f, a3 = 0.f;
    float a4 = 0.f, a5 = 0.f, a6 = 0.f, a7 = 0.f;
    const int end = beg + deg;
    for (int e = beg + g; e < end; e += 16) {
        int s = (int)esrc[e];
        uint4 u = *(const uint4*)&t2[(size_t)s * 32 + c * 8];
        a0 += bf_lo(u.x); a1 += bf_hi(u.x);
        a2 += bf_lo(u.y); a3 += bf_hi(u.y);
        a4 += bf_lo(u.z); a5 += bf_hi(u.z);
        a6 += bf_lo(u.w); a7 += bf_hi(u.w);
    }
    #pragma unroll
    for (int d = 4; d <= 32; d <<= 1) {
        a0 += __shfl_xor(a0, d); a1 += __shfl_xor(a1, d);
        a2 += __shfl_xor(a2, d); a3 += __shfl_xor(a3, d);
        a4 += __shfl_xor(a4, d); a5 += __shfl_xor(a5, d);
        a6 += __shfl_xor(a6, d); a7 += __shfl_xor(a7, d);
    }
    if (lane < 4) {
        float f = 1.f / (float)deg;
        float4 o0 = *(const float4*)&outp[(size_t)v * 32 + c * 8];
        float4 o1 = *(const float4*)&outp[(size_t)v * 32 + c * 8 + 4];
        o0.x += a0*f; o0.y += a1*f; o0.z += a2*f; o0.w += a3*f;
        o1.x += a4*f; o1.y += a5*f; o1.z += a6*f; o1.w += a7*f;
        *(float4*)&outp[(size_t)v * 32 + c * 8]     = o0;
        *(float4*)&outp[(size_t)v * 32 + c * 8 + 4] = o1;
    }
}

extern "C" void kernel_launch(void* const* d_in, const int* in_sizes, int n_in,
                              void* d_out, int out_size, void* d_ws, size_t ws_size,
                              hipStream_t stream) {
    const float* feat = (const float*)d_in[0];
    const int*   src  = (const int*)d_in[1];
    const int*   dst  = (const int*)d_in[2];
    const float* ws1  = (const float*)d_in[3];
    const float* wn1  = (const float*)d_in[4];
    const float* b1   = (const float*)d_in[5];
    const float* ws2  = (const float*)d_in[6];
    const float* wn2  = (const float*)d_in[7];
    const float* b2   = (const float*)d_in[8];
    float* out = (float*)d_out;

    const int N = in_sizes[0] / 64;
    const int E = in_sizes[1];
    const int nB = (N + SPAN - 1) >> SPAN_SHIFT;

    int cap = ((E + nB - 1) / nB);
    cap = ((cap + cap / 4) + 63) & ~63;
    {
        size_t fixedBytes = NBMAX * 4 + (size_t)N * 8
                          + (size_t)N * 64 * 4 * 2   // mean + h
                          + (size_t)N * 64 * 2       // xh (aliases t2)
                          + 4096;
        size_t remain = (ws_size > fixedBytes) ? (ws_size - fixedBytes) : 0;
        size_t capMax = remain / ((size_t)nB * 4);
        if ((size_t)cap > capMax) cap = (int)(capMax & ~(size_t)3);
    }

    char* base = (char*)d_ws;
    int* cursor = (int*)base;                               // [NBMAX]
    unsigned int* pairs = (unsigned int*)(base + NBMAX * 4);
    size_t sOff = ((size_t)NBMAX * 4 + (size_t)nB * cap * 4 + 255) & ~(size_t)255;
    int* starts = (int*)(base + sOff);                      // [N]
    int* degs   = starts + N;                               // [N]
    size_t mOff = (sOff + (size_t)N * 8 + 255) & ~(size_t)255;
    float* mean = (float*)(base + mOff);                    // [N,64] f32
    float* h    = mean + (size_t)N * 64;                    // [N,64] f32
    unsigned short* xh = (unsigned short*)(h + (size_t)N * 64);  // [N,64] bf16
    unsigned short* t2 = xh;                                // [N,32] bf16 (aliases xh; xh dead by then)

    const long total8 = (long)N * 64 / 8;
    k_cvt_zero<<<(int)((total8 + 255) / 256), 256, 0, stream>>>(feat, xh, cursor, total8);

    const int pblocks = (E + PART_BLOCK * PART_EPT - 1) / (PART_BLOCK * PART_EPT);
    k_partition<<<pblocks, PART_BLOCK, 0, stream>>>(src, dst, cursor, pairs, E, cap);
    k_bucket_csr<<<nB, 256, (size_t)cap * 4, stream>>>(pairs, cursor, starts, degs, N, cap);

    const int gblocks = (N + 3) / 4;
    const int tblocks = (N + 127) / 128;

    k_gather_b64<<<gblocks, 256, 0, stream>>>(xh, pairs, starts, degs, mean, N);
    k_gemm_l1<<<tblocks, 256, 0, stream>>>(feat, mean, ws1, wn1, b1, ws2, wn2, b2,
                                           h, t2, out, N);
    k_gather_b32add<<<gblocks, 256, 0, stream>>>(t2, pairs, starts, degs, out, N);
}

// Round 9
// 202.572 us; speedup vs baseline: 5.1500x; 1.1678x over previous
//
#include <hip/hip_runtime.h>

// GraphSAGE 2-layer. Gathers: bf16 tables, fp32 accum. GEMMs: bf16 MFMA
// (16x16x32, fp32 acc) -- fp32 VALU ceiling (157TF) was the R7 limiter.
// mean(x)@W == mean(x@W): layer-2 gathers 64B rows of t2=bf16(h@Wn2).
// Pipeline (memset + 5 kernels):
//   memset cursor=0
//   k_partition  : + cvt feat->xh bf16 (grid-strided) + blocks 0-11
//                  transpose/bf16 the 3 weight mats into wt[c][k];
//                  buckets edges by dst>>7 into padded slabs.
//   k_bucket_csr : per-bucket LDS counting sort -> starts/degs.
//   k_gather_b64 : wave/node mean of xh rows -> meanh bf16.
//   k_gemm_mfma  : MFMA: acc = xh@Ws1 + meanh@Wn1; h=relu(+b1) kept in LDS
//                  (A-layout roundtrip); acc2 = h@[Wn2|Ws2] -> t2 bf16,
//                  out = +b2.  h global array eliminated (dead).
//   k_gather_b32add: mean of t2 rows, out += meanT.
// R8 FIX: sWt staging covered only chunks {0,16,32,48} of each 64-short row
// (uint4 = 8 shorts) -> half of LDS weights uninitialized -> NaN. Now 8
// chunks per row.

#define SPAN        128
#define SPAN_SHIFT  7
#define PART_BLOCK  1024
#define PART_EPT    4
#define NBMAX       1024
#define LDS_S       72

typedef __attribute__((ext_vector_type(8))) short bf16x8;
typedef __attribute__((ext_vector_type(4))) float f32x4;

__device__ __forceinline__ unsigned bf16_rne(float f) {
    unsigned u = __float_as_uint(f);
    return (u + 0x7FFFu + ((u >> 16) & 1u)) >> 16;
}
__device__ __forceinline__ float bf_lo(unsigned u) { return __uint_as_float(u << 16); }
__device__ __forceinline__ float bf_hi(unsigned u) { return __uint_as_float(u & 0xFFFF0000u); }

// Partition + feat->bf16 cvt + weight transpose.
// wt layout: [mat][c][k] bf16, mat0=Ws1^T, mat1=Wn1^T, mat2=[Wn2|Ws2]^T.
__global__ __launch_bounds__(PART_BLOCK) void k_partition(
    const int* __restrict__ src, const int* __restrict__ dst,
    int* __restrict__ cursor, unsigned int* __restrict__ pairs,
    int E, int cap,
    const float* __restrict__ feat, unsigned short* __restrict__ xh, long total8,
    const float* __restrict__ ws1, const float* __restrict__ wn1,
    const float* __restrict__ ws2, const float* __restrict__ wn2,
    unsigned short* __restrict__ wt)
{
    const int tid = threadIdx.x;
    // cvt feat -> xh (grid-strided uint4 chunks of 8 bf16)
    for (long i = (long)blockIdx.x * PART_BLOCK + tid; i < total8;
         i += (long)gridDim.x * PART_BLOCK) {
        const float4 a = ((const float4*)feat)[i * 2];
        const float4 b = ((const float4*)feat)[i * 2 + 1];
        uint4 o;
        o.x = bf16_rne(a.x) | (bf16_rne(a.y) << 16);
        o.y = bf16_rne(a.z) | (bf16_rne(a.w) << 16);
        o.z = bf16_rne(b.x) | (bf16_rne(b.y) << 16);
        o.w = bf16_rne(b.z) | (bf16_rne(b.w) << 16);
        ((uint4*)xh)[i] = o;
    }
    // weight transpose+cvt: 3*64*64 = 12288 elems over blocks 0..11
    if (blockIdx.x < 12) {
        int j = blockIdx.x * PART_BLOCK + tid;   // < 12288
        int mat = j >> 12, rem = j & 4095;
        int c = rem >> 6, k = rem & 63;
        float v;
        if (mat == 0)      v = ws1[k * 64 + c];
        else if (mat == 1) v = wn1[k * 64 + c];
        else               v = (c < 32) ? wn2[k * 32 + c] : ws2[k * 32 + (c - 32)];
        wt[(mat << 12) + (c << 6) + k] = (unsigned short)bf16_rne(v);
    }

    __shared__ int cnt[NBMAX];
    __shared__ int gbase[NBMAX];
    __shared__ int lcur[NBMAX];
    cnt[tid] = 0; lcur[tid] = 0;
    __syncthreads();

    int sv[PART_EPT], bv[PART_EPT];
    const int e0 = blockIdx.x * (PART_BLOCK * PART_EPT) + tid;
    #pragma unroll
    for (int j = 0; j < PART_EPT; ++j) {
        int e = e0 + j * PART_BLOCK;
        bv[j] = -1;
        if (e < E) {
            int s = src[e], d = dst[e];
            bv[j] = d >> SPAN_SHIFT;
            sv[j] = s | ((d & (SPAN - 1)) << 24);
            atomicAdd(&cnt[bv[j]], 1);
        }
    }
    __syncthreads();
    if (cnt[tid] > 0) gbase[tid] = atomicAdd(&cursor[tid], cnt[tid]);
    __syncthreads();
    #pragma unroll
    for (int j = 0; j < PART_EPT; ++j) {
        if (bv[j] >= 0) {
            int r = gbase[bv[j]] + atomicAdd(&lcur[bv[j]], 1);
            if (r < cap) pairs[(size_t)bv[j] * cap + r] = (unsigned int)sv[j];
        }
    }
}

// Per bucket: LDS counting sort by dlocal, in-place coalesced writeback.
__global__ __launch_bounds__(256) void k_bucket_csr(
    unsigned int* __restrict__ pairs,
    const int* __restrict__ cursor,
    int* __restrict__ starts, int* __restrict__ degs,
    int N, int cap)
{
    __shared__ int cnt[SPAN];
    __shared__ int pref[SPAN];
    __shared__ int lcur[SPAN];
    extern __shared__ unsigned int sorted[];
    const int tid = threadIdx.x;
    const int b = blockIdx.x;
    if (tid < SPAN) { cnt[tid] = 0; lcur[tid] = 0; }
    __syncthreads();

    int m = cursor[b]; if (m > cap) m = cap;
    const size_t pb = (size_t)b * cap;

    for (int i = tid; i < m; i += 256)
        atomicAdd(&cnt[pairs[pb + i] >> 24], 1);
    __syncthreads();

    if (tid < SPAN) pref[tid] = cnt[tid];
    __syncthreads();
    for (int off = 1; off < SPAN; off <<= 1) {
        int v = 0;
        if (tid < SPAN && tid >= off) v = pref[tid - off];
        __syncthreads();
        if (tid < SPAN) pref[tid] += v;
        __syncthreads();
    }

    for (int i = tid; i < m; i += 256) {
        unsigned int p = pairs[pb + i];
        int r = p >> 24;
        int base = (r == 0) ? 0 : pref[r - 1];
        int pos = base + atomicAdd(&lcur[r], 1);
        sorted[pos] = p & 0xFFFFFFu;
    }
    __syncthreads();
    for (int i = tid; i < m; i += 256) pairs[pb + i] = sorted[i];
    if (tid < SPAN) {
        int node = (b << SPAN_SHIFT) + tid;
        if (node < N) {
            int base = (tid == 0) ? 0 : pref[tid - 1];
            starts[node] = (int)pb + base;
            degs[node]   = cnt[tid];
        }
    }
}

// Wave/node mean over bf16 [*,64] rows -> meanh bf16. 8 rows/instr.
__global__ __launch_bounds__(256) void k_gather_b64(
    const unsigned short* __restrict__ xh,
    const unsigned int* __restrict__ esrc,
    const int* __restrict__ starts, const int* __restrict__ degs,
    unsigned short* __restrict__ meanh, int n)
{
    const int w = threadIdx.x >> 6, lane = threadIdx.x & 63;
    const int v = blockIdx.x * 4 + w;
    if (v >= n) return;
    const int beg = starts[v], deg = degs[v];
    const int g = lane >> 3, c = lane & 7;
    float a0 = 0.f, a1 = 0.f, a2 = 0.f, a3 = 0.f;
    float a4 = 0.f, a5 = 0.f, a6 = 0.f, a7 = 0.f;
    const int end = beg + deg;
    for (int e = beg + g; e < end; e += 8) {
        int s = (int)esrc[e];
        uint4 u = *(const uint4*)&xh[(size_t)s * 64 + c * 8];
        a0 += bf_lo(u.x); a1 += bf_hi(u.x);
        a2 += bf_lo(u.y); a3 += bf_hi(u.y);
        a4 += bf_lo(u.z); a5 += bf_hi(u.z);
        a6 += bf_lo(u.w); a7 += bf_hi(u.w);
    }
    #pragma unroll
    for (int d = 8; d <= 32; d <<= 1) {
        a0 += __shfl_xor(a0, d); a1 += __shfl_xor(a1, d);
        a2 += __shfl_xor(a2, d); a3 += __shfl_xor(a3, d);
        a4 += __shfl_xor(a4, d); a5 += __shfl_xor(a5, d);
        a6 += __shfl_xor(a6, d); a7 += __shfl_xor(a7, d);
    }
    if (lane < 8) {
        float f = deg ? 1.f / (float)deg : 0.f;
        uint4 o;
        o.x = bf16_rne(a0 * f) | (bf16_rne(a1 * f) << 16);
        o.y = bf16_rne(a2 * f) | (bf16_rne(a3 * f) << 16);
        o.z = bf16_rne(a4 * f) | (bf16_rne(a5 * f) << 16);
        o.w = bf16_rne(a6 * f) | (bf16_rne(a7 * f) << 16);
        *(uint4*)&meanh[(size_t)v * 64 + c * 8] = o;
    }
}

// MFMA GEMM: 128-row tile, 4 waves, each wave 32 rows x 64 cols.
// A-frag: A[m=lane&15][k=quad*8+j]; B-frag: B[k=quad*8+j][n=lane&15];
// C/D: col=lane&15, row=quad*4+reg.
__global__ __launch_bounds__(256) void k_gemm_mfma(
    const unsigned short* __restrict__ xh,     // [N,64] bf16
    const unsigned short* __restrict__ meanh,  // [N,64] bf16
    const unsigned short* __restrict__ wt,     // [3][64][64] bf16 c-major
    const float* __restrict__ b1, const float* __restrict__ b2,
    unsigned short* __restrict__ t2,           // [N,32] bf16
    float* __restrict__ outp,                  // [N,32] f32
    int n)
{
    __shared__ __align__(16) unsigned short sX[128 * LDS_S];      // 18432 B
    __shared__ __align__(16) unsigned short sWt[3 * 64 * LDS_S];  // 27648 B
    const int tid  = threadIdx.x;
    const int w    = tid >> 6, lane = tid & 63;
    const int quad = lane >> 4, lm = lane & 15;
    const int gm0  = blockIdx.x * 128;
    const int rowA = w * 32;

    // stage all 3 transposed weight mats: 192 rows x 8 chunks(16B = 8 shorts)
    for (int i = tid; i < 1536; i += 256) {
        int r  = i >> 3;
        int k0 = (i & 7) << 3;
        *(uint4*)&sWt[r * LDS_S + k0] = *(const uint4*)&wt[(r << 6) + k0];
    }
    // stage xh tile: 128 rows x 8 chunks(16B)
    for (int i = tid; i < 1024; i += 256) {
        int m = i >> 3, k0 = (i & 7) << 3;
        int gm = gm0 + m;
        uint4 v = make_uint4(0, 0, 0, 0);
        if (gm < n) v = *(const uint4*)&xh[(size_t)gm * 64 + k0];
        *(uint4*)&sX[m * LDS_S + k0] = v;
    }
    __syncthreads();

    f32x4 acc[2][4];
    #pragma unroll
    for (int mt = 0; mt < 2; ++mt)
        #pragma unroll
        for (int nt = 0; nt < 4; ++nt) acc[mt][nt] = (f32x4){0.f, 0.f, 0.f, 0.f};

    // loop 1a: acc += X @ Ws1
    #pragma unroll
    for (int kt = 0; kt < 2; ++kt) {
        bf16x8 a0 = *(const bf16x8*)&sX[(rowA + lm) * LDS_S + kt * 32 + quad * 8];
        bf16x8 a1 = *(const bf16x8*)&sX[(rowA + 16 + lm) * LDS_S + kt * 32 + quad * 8];
        #pragma unroll
        for (int nt = 0; nt < 4; ++nt) {
            bf16x8 b = *(const bf16x8*)&sWt[(nt * 16 + lm) * LDS_S + kt * 32 + quad * 8];
            acc[0][nt] = __builtin_amdgcn_mfma_f32_16x16x32_bf16(a0, b, acc[0][nt], 0, 0, 0);
            acc[1][nt] = __builtin_amdgcn_mfma_f32_16x16x32_bf16(a1, b, acc[1][nt], 0, 0, 0);
        }
    }
    __syncthreads();
    // restage with meanh
    for (int i = tid; i < 1024; i += 256) {
        int m = i >> 3, k0 = (i & 7) << 3;
        int gm = gm0 + m;
        uint4 v = make_uint4(0, 0, 0, 0);
        if (gm < n) v = *(const uint4*)&meanh[(size_t)gm * 64 + k0];
        *(uint4*)&sX[m * LDS_S + k0] = v;
    }
    __syncthreads();
    // loop 1b: acc += M @ Wn1
    #pragma unroll
    for (int kt = 0; kt < 2; ++kt) {
        bf16x8 a0 = *(const bf16x8*)&sX[(rowA + lm) * LDS_S + kt * 32 + quad * 8];
        bf16x8 a1 = *(const bf16x8*)&sX[(rowA + 16 + lm) * LDS_S + kt * 32 + quad * 8];
        #pragma unroll
        for (int nt = 0; nt < 4; ++nt) {
            bf16x8 b = *(const bf16x8*)&sWt[(64 + nt * 16 + lm) * LDS_S + kt * 32 + quad * 8];
            acc[0][nt] = __builtin_amdgcn_mfma_f32_16x16x32_bf16(a0, b, acc[0][nt], 0, 0, 0);
            acc[1][nt] = __builtin_amdgcn_mfma_f32_16x16x32_bf16(a1, b, acc[1][nt], 0, 0, 0);
        }
    }
    __syncthreads();   // all waves done reading meanh tile before h overwrite

    // epilogue 1: h = relu(acc + b1[col]) -> sX (own rows only; no barrier
    // needed before loop 2 since each wave reads only its own 32 rows)
    #pragma unroll
    for (int nt = 0; nt < 4; ++nt) {
        float bb = b1[nt * 16 + lm];
        #pragma unroll
        for (int mt = 0; mt < 2; ++mt) {
            int rbase = rowA + mt * 16 + quad * 4;
            #pragma unroll
            for (int r = 0; r < 4; ++r) {
                float hv = fmaxf(acc[mt][nt][r] + bb, 0.f);
                sX[(rbase + r) * LDS_S + nt * 16 + lm] = (unsigned short)bf16_rne(hv);
            }
        }
    }

    // loop 2: acc2 = H @ [Wn2|Ws2]
    f32x4 acc2[2][4];
    #pragma unroll
    for (int mt = 0; mt < 2; ++mt)
        #pragma unroll
        for (int nt = 0; nt < 4; ++nt) acc2[mt][nt] = (f32x4){0.f, 0.f, 0.f, 0.f};
    #pragma unroll
    for (int kt = 0; kt < 2; ++kt) {
        bf16x8 a0 = *(const bf16x8*)&sX[(rowA + lm) * LDS_S + kt * 32 + quad * 8];
        bf16x8 a1 = *(const bf16x8*)&sX[(rowA + 16 + lm) * LDS_S + kt * 32 + quad * 8];
        #pragma unroll
        for (int nt = 0; nt < 4; ++nt) {
            bf16x8 b = *(const bf16x8*)&sWt[(128 + nt * 16 + lm) * LDS_S + kt * 32 + quad * 8];
            acc2[0][nt] = __builtin_amdgcn_mfma_f32_16x16x32_bf16(a0, b, acc2[0][nt], 0, 0, 0);
            acc2[1][nt] = __builtin_amdgcn_mfma_f32_16x16x32_bf16(a1, b, acc2[1][nt], 0, 0, 0);
        }
    }

    // epilogue 2: cols 0-31 -> t2 bf16; cols 32-63 -> out = +b2 (f32)
    #pragma unroll
    for (int mt = 0; mt < 2; ++mt) {
        int rbase = gm0 + rowA + mt * 16 + quad * 4;
        #pragma unroll
        for (int nt = 0; nt < 2; ++nt) {
            #pragma unroll
            for (int r = 0; r < 4; ++r) {
                int gm = rbase + r;
                if (gm < n)
                    t2[(size_t)gm * 32 + nt * 16 + lm] =
                        (unsigned short)bf16_rne(acc2[mt][nt][r]);
            }
        }
        #pragma unroll
        for (int nt = 2; nt < 4; ++nt) {
            float bb = b2[(nt - 2) * 16 + lm];
            #pragma unroll
            for (int r = 0; r < 4; ++r) {
                int gm = rbase + r;
                if (gm < n)
                    outp[(size_t)gm * 32 + (nt - 2) * 16 + lm] = acc2[mt][nt][r] + bb;
            }
        }
    }
}

// Wave/node mean over bf16 [*,32] rows (16 rows/instr); out += meanT.
__global__ __launch_bounds__(256) void k_gather_b32add(
    const unsigned short* __restrict__ t2,
    const unsigned int* __restrict__ esrc,
    const int* __restrict__ starts, const int* __restrict__ degs,
    float* __restrict__ outp, int n)
{
    const int w = threadIdx.x >> 6, lane = threadIdx.x & 63;
    const int v = blockIdx.x * 4 + w;
    if (v >= n) return;
    const int beg = starts[v], deg = degs[v];
    if (deg == 0) return;
    const int g = lane >> 2, c = lane & 3;
    float a0 = 0.f, a1 = 0.f, a2 = 0.f, a3 = 0.f;
    float a4 = 0.f, a5 = 0.f, a6 = 0.f, a7 = 0.f;
    const int end = beg + deg;
    for (int e = beg + g; e < end; e += 16) {
        int s = (int)esrc[e];
        uint4 u = *(const uint4*)&t2[(size_t)s * 32 + c * 8];
        a0 += bf_lo(u.x); a1 += bf_hi(u.x);
        a2 += bf_lo(u.y); a3 += bf_hi(u.y);
        a4 += bf_lo(u.z); a5 += bf_hi(u.z);
        a6 += bf_lo(u.w); a7 += bf_hi(u.w);
    }
    #pragma unroll
    for (int d = 4; d <= 32; d <<= 1) {
        a0 += __shfl_xor(a0, d); a1 += __shfl_xor(a1, d);
        a2 += __shfl_xor(a2, d); a3 += __shfl_xor(a3, d);
        a4 += __shfl_xor(a4, d); a5 += __shfl_xor(a5, d);
        a6 += __shfl_xor(a6, d); a7 += __shfl_xor(a7, d);
    }
    if (lane < 4) {
        float f = 1.f / (float)deg;
        float4 o0 = *(const float4*)&outp[(size_t)v * 32 + c * 8];
        float4 o1 = *(const float4*)&outp[(size_t)v * 32 + c * 8 + 4];
        o0.x += a0 * f; o0.y += a1 * f; o0.z += a2 * f; o0.w += a3 * f;
        o1.x += a4 * f; o1.y += a5 * f; o1.z += a6 * f; o1.w += a7 * f;
        *(float4*)&outp[(size_t)v * 32 + c * 8]     = o0;
        *(float4*)&outp[(size_t)v * 32 + c * 8 + 4] = o1;
    }
}

extern "C" void kernel_launch(void* const* d_in, const int* in_sizes, int n_in,
                              void* d_out, int out_size, void* d_ws, size_t ws_size,
                              hipStream_t stream) {
    const float* feat = (const float*)d_in[0];
    const int*   src  = (const int*)d_in[1];
    const int*   dst  = (const int*)d_in[2];
    const float* ws1  = (const float*)d_in[3];
    const float* wn1  = (const float*)d_in[4];
    const float* b1   = (const float*)d_in[5];
    const float* ws2  = (const float*)d_in[6];
    const float* wn2  = (const float*)d_in[7];
    const float* b2   = (const float*)d_in[8];
    float* out = (float*)d_out;

    const int N = in_sizes[0] / 64;
    const int E = in_sizes[1];
    const int nB = (N + SPAN - 1) >> SPAN_SHIFT;

    int cap = ((E + nB - 1) / nB);
    cap = ((cap + cap / 4) + 63) & ~63;
    {
        size_t fixedBytes = NBMAX * 4 + 3 * 4096 * 2 + (size_t)N * 8
                          + (size_t)N * 64 * 2 * 2   // meanh + xh
                          + (size_t)N * 32 * 2       // t2
                          + 8192;
        size_t remain = (ws_size > fixedBytes) ? (ws_size - fixedBytes) : 0;
        size_t capMax = remain / ((size_t)nB * 4);
        if ((size_t)cap > capMax) cap = (int)(capMax & ~(size_t)3);
    }

    char* base = (char*)d_ws;
    int* cursor = (int*)base;                                    // [1024]
    unsigned short* wt = (unsigned short*)(base + NBMAX * 4);    // [3][64][64] bf16
    unsigned int* pairs = (unsigned int*)(base + NBMAX * 4 + 24576);
    size_t sOff = ((size_t)NBMAX * 4 + 24576 + (size_t)nB * cap * 4 + 255) & ~(size_t)255;
    int* starts = (int*)(base + sOff);                           // [N]
    int* degs   = starts + N;                                    // [N]
    size_t mOff = (sOff + (size_t)N * 8 + 255) & ~(size_t)255;
    unsigned short* meanh = (unsigned short*)(base + mOff);      // [N,64] bf16
    unsigned short* xh    = meanh + (size_t)N * 64;              // [N,64] bf16
    unsigned short* t2    = xh + (size_t)N * 64;                 // [N,32] bf16

    hipMemsetAsync(cursor, 0, NBMAX * 4, stream);

    const long total8 = (long)N * 64 / 8;
    const int pblocks = (E + PART_BLOCK * PART_EPT - 1) / (PART_BLOCK * PART_EPT);
    k_partition<<<pblocks, PART_BLOCK, 0, stream>>>(
        src, dst, cursor, pairs, E, cap,
        feat, xh, total8, ws1, wn1, ws2, wn2, wt);
    k_bucket_csr<<<nB, 256, (size_t)cap * 4, stream>>>(pairs, cursor, starts, degs, N, cap);

    const int gblocks = (N + 3) / 4;
    const int tblocks = (N + 127) / 128;

    k_gather_b64<<<gblocks, 256, 0, stream>>>(xh, pairs, starts, degs, meanh, N);
    k_gemm_mfma<<<tblocks, 256, 0, stream>>>(xh, meanh, wt, b1, b2, t2, out, N);
    k_gather_b32add<<<gblocks, 256, 0, stream>>>(t2, pairs, starts, degs, out, N);
}